// Round 8
// baseline (394.440 us; speedup 1.0000x reference)
//
#include <hip/hip_runtime.h>
#include <hip/hip_fp16.h>

#define HW 36864      // 192*192
#define IMGS 128      // B*C

typedef _Float16 h16;
typedef _Float16 v8h __attribute__((ext_vector_type(8)));
typedef _Float16 v2h __attribute__((ext_vector_type(2)));
typedef float v4f __attribute__((ext_vector_type(4)));

static __device__ __forceinline__ int imax(int a, int b) { return a > b ? a : b; }
static __device__ __forceinline__ int imin(int a, int b) { return a < b ? a : b; }

__device__ __constant__ float LIFT_C[6] = {
  -0.5f, 0.25f,                                            // bior53
  -1.586134342f, -0.05298011854f, 0.8829110762f, 0.4435068522f  // bior97
};
__device__ __constant__ int FIR_L[4]   = {8, 12, 12, 30};
__device__ __constant__ int FIR_PA[4]  = {2, 4, 4, 13};
__device__ __constant__ int FIR_OFF[4] = {0, 8, 20, 32};

// raw (unnormalized) FIR lowpass filters concatenated: db4(8) db6(12) sym6(12) coif5(30)
__device__ constexpr float FIRC[62] = {
  -0.0105974017850021f, 0.0328830116668852f, 0.0308413818355607f, -0.1870348117188811f,
  -0.0279837694169839f, 0.6308807679295904f, 0.7148465705529155f, 0.2303778133088964f,
  0.00107730108499558f, -0.00477725751101065f, -0.0005538422009938f, 0.03158203931748603f,
  0.02752286553030533f, -0.0975016055873225f, -0.12976686756709563f, 0.22626469396544f,
  0.3152503517092432f, -0.7511339080210959f, 0.4946238903984534f, 0.1115407433501095f,
  -0.007800708325034148f, 0.001767711864242804f, 0.04472490177066578f, -0.02106029251230056f,
  -0.0726375227866f, 0.3379294217282401f, 0.787641141030194f, 0.4910559419267466f,
  -0.048311742585632f, -0.1179901111484105f, 0.00349071208421747f, 0.01540410932702737f,
  -3.459977283621256e-05f, -7.098330313814114e-05f, 0.0004662169601128863f, 0.001117518770890601f,
  -0.002574517688750223f, -0.00900797613666158f, 0.015880544863615904f, 0.03455502757306163f,
  -0.08230192710688598f, -0.07179982161931202f, 0.42848347637761874f, 0.7937772226256206f,
  0.4051769024096169f, -0.06112339000267287f, -0.06577191128185562f, 0.023452696141836267f,
  0.007782596427325418f, -0.003793512864491014f, -0.0002606761356811993f, 0.000107502882505652f,
  1.10319778524429e-05f, -5.520763127949e-06f, -1.0682196848076e-06f, 5.236425333584e-07f,
  1.125098976034e-07f, -5.417490769329e-08f, -8.8631e-09f, 4.2921e-09f, 6.7e-10f, -3.2e-10f,
};

// ---------------- gate: 1x1 conv -> relu -> 1x1 conv -> softmax -> renorm (fp16 out) ----------------
__global__ __launch_bounds__(256) void k_gate(
    const float* __restrict__ x, const float* __restrict__ w1, const float* __restrict__ b1,
    const float* __restrict__ w2, const float* __restrict__ b2, h16* __restrict__ gate)
{
  __shared__ float w1s[256], b1s[8], w2s[48], b2s[6];
  int tid = threadIdx.x;
  w1s[tid] = w1[tid];
  if (tid < 8)  b1s[tid] = b1[tid];
  if (tid < 48) w2s[tid] = w2[tid];
  if (tid < 6)  b2s[tid] = b2[tid];
  __syncthreads();
  int px = blockIdx.x * 256 + tid;        // exactly 4*HW threads
  int b = px / HW, p = px - b * HW;
  const float* xb = x + (size_t)b * 32 * HW + p;
  float xv[32];
#pragma unroll
  for (int c = 0; c < 32; ++c) xv[c] = xb[(size_t)c * HW];
  float hb[8];
#pragma unroll
  for (int j = 0; j < 8; ++j) {
    float s = b1s[j];
#pragma unroll
    for (int c = 0; c < 32; ++c) s += w1s[j * 32 + c] * xv[c];
    hb[j] = fmaxf(s, 0.f);
  }
  float e[6], mx = -1e30f;
#pragma unroll
  for (int k = 0; k < 6; ++k) {
    float s = b2s[k];
#pragma unroll
    for (int j = 0; j < 8; ++j) s += w2s[k * 8 + j] * hb[j];
    e[k] = s; mx = fmaxf(mx, s);
  }
  float se = 0.f;
#pragma unroll
  for (int k = 0; k < 6; ++k) { e[k] = expf(e[k] - mx); se += e[k]; }
  float inv = 1.f / se, s2 = 0.f;
#pragma unroll
  for (int k = 0; k < 6; ++k) { e[k] *= inv; s2 += e[k]; }
  float inv2 = 1.f / (s2 + 1e-12f);
  h16* gp = gate + (size_t)b * 6 * HW + p;
#pragma unroll
  for (int k = 0; k < 6; ++k) gp[(size_t)k * HW] = (h16)(e[k] * inv2);
}

// ---------------- build the 12 operator matrices (fp16, 192x192 row-major [out][in]) ----------------
__global__ __launch_bounds__(64) void k_build(
    h16* __restrict__ Kall, const float* __restrict__ s53A, const float* __restrict__ s53D,
    const float* __restrict__ s97A, const float* __restrict__ s97D)
{
  const int col = blockIdx.x;      // 0..191 (input index)
  const int mat = blockIdx.y;      // 0..11
  const int cand = mat >> 1, side = mat & 1;
  const int tid = threadIdx.x;
  h16* out = Kall + (size_t)mat * HW;
  if (cand < 4) {
    const int Lf = FIR_L[cand], PA = FIR_PA[cand], OFF = FIR_OFF[cand];
    float ss = 0.f;
    for (int j = 0; j < Lf; ++j) ss += FIRC[OFF + j] * FIRC[OFF + j];
    const float invn = 1.f / (sqrtf(ss) + 1e-12f);
    for (int i = tid; i < 192; i += 64) {
      const int d = (i < 96) ? 1 : 2;
      const int q0 = i - d;
      const int i0 = imax(q0, 0), i1 = imin(q0 + 1, 189);
      const float tt = (float)d - (float)(2 * i + 1) * (1.f / 192.f);
      float c0 = 0.f, c1 = 0.f;
      for (int j = 0; j < Lf; ++j) {
        float fj = side ? (((j & 1) ? -1.f : 1.f) * FIRC[OFF + Lf - 1 - j]) : FIRC[OFF + j];
        fj *= invn;
        int r0 = i0 + j - PA; r0 = r0 < 0 ? -r0 : (r0 > 191 ? 382 - r0 : r0);
        int r1 = i1 + j - PA; r1 = r1 < 0 ? -r1 : (r1 > 191 ? 382 - r1 : r1);
        if (r0 == col) c0 += fj;
        if (r1 == col) c1 += fj;
      }
      out[(size_t)i * 192 + col] = (h16)((1.f - tt) * c0 + tt * c1);
    }
  } else {
    __shared__ float yb[192];
    __shared__ float sb[96];
    yb[tid] = 0.f; yb[tid + 64] = 0.f; yb[tid + 128] = 0.f;
    __syncthreads();
    if (tid == 0) yb[col] = 1.f;
    __syncthreads();
    const int c97 = (cand == 5);
    const int base = c97 ? 2 : 0, ns = c97 ? 4 : 2;
    for (int s = 0; s < ns; ++s) {
      const float cf = LIFT_C[base + s] * 0.5f;
      for (int j = tid; j < 96; j += 64) {
        int jm = (j == 0) ? 1 : j - 1, jp = (j == 95) ? 94 : j + 1;
        if ((s & 1) == 0) yb[2 * j + 1] += cf * (yb[2 * jm] + yb[2 * jp]);
        else              yb[2 * j]     += cf * (yb[2 * jm + 1] + yb[2 * jp + 1]);
      }
      __syncthreads();
    }
    const float sA = c97 ? s97A[0] : s53A[0];
    const float sD = c97 ? s97D[0] : s53D[0];
    for (int u = tid; u < 96; u += 64)
      sb[u] = side ? sD * yb[2 * u + 1] : sA * yb[2 * u];
    __syncthreads();
    for (int i = tid; i < 192; i += 64) {
      const int u0 = (i >> 1) + (i & 1) - 1;
      const float tt = (i & 1) ? 0.25f : 0.75f;
      const int a0 = imax(u0, 0), a1 = imin(u0 + 1, 95);
      out[(size_t)i * 192 + col] = (h16)((1.f - tt) * sb[a0] + tt * sb[a1]);
    }
  }
}

// ---------------- pass W: PT[plane][img][w'][h] = sum_w K[plane][w'][w] * x[img][h][w] ----------
// grid (12 m-tiles, 128 imgs) = 1536 SINGLE-WAVE blocks (64 thr). No LDS, no barriers.
// Per h-chunk: batch-load b[4][3] (12 distinct v8h regs -> 12 loads forced in flight; the
// R4 lesson: per-use loads serialize, named-register batches don't), then loop 12 planes
// reusing b (a from L2-hot Kall). fp32 x converted in-register (x16 buffer dropped so the
// workspace stays at the proven 153.6 MB). C[r] at (m0+quad*4+r, h0+lm) -> PT store is
// 16-lane 32B-contiguous (operand-order rule proven in R5).
__global__ __launch_bounds__(64) void k_gw(
    const float* __restrict__ x, const h16* __restrict__ Kall, h16* __restrict__ PT)
{
  const int mt = blockIdx.x, img = blockIdx.y;
  const int lane = threadIdx.x;
  const int lm = lane & 15, quad = lane >> 4;
  const int m0 = mt * 16;                        // w' tile base
  int ktr = (m0 - 24) >> 5; ktr = ktr < 0 ? 0 : (ktr > 3 ? 3 : ktr);   // 3-slot band window
  const float* xi = x + (size_t)img * HW;
  for (int hc = 0; hc < 3; ++hc) {
    v8h b[4][3];
#pragma unroll
    for (int j = 0; j < 4; ++j)
#pragma unroll
      for (int kt = 0; kt < 3; ++kt) {
        const float* xr = xi + (size_t)(hc * 64 + j * 16 + lm) * 192 + (ktr + kt) * 32 + quad * 8;
        float4 u0 = *(const float4*)xr;
        float4 u1 = *(const float4*)(xr + 4);
        v8h t;
        t[0] = (h16)u0.x; t[1] = (h16)u0.y; t[2] = (h16)u0.z; t[3] = (h16)u0.w;
        t[4] = (h16)u1.x; t[5] = (h16)u1.y; t[6] = (h16)u1.z; t[7] = (h16)u1.w;
        b[j][kt] = t;
      }
#pragma unroll 2
    for (int plane = 0; plane < 12; ++plane) {
      const h16* KW = Kall + (size_t)plane * HW + (size_t)(m0 + lm) * 192 + ktr * 32 + quad * 8;
      v8h a0 = *(const v8h*)(KW);
      v8h a1 = *(const v8h*)(KW + 32);
      v8h a2 = *(const v8h*)(KW + 64);
      v4f C[4];
#pragma unroll
      for (int j = 0; j < 4; ++j) C[j] = (v4f){0.f, 0.f, 0.f, 0.f};
#pragma unroll
      for (int j = 0; j < 4; ++j) {
        C[j] = __builtin_amdgcn_mfma_f32_16x16x32_f16(a0, b[j][0], C[j], 0, 0, 0);
        C[j] = __builtin_amdgcn_mfma_f32_16x16x32_f16(a1, b[j][1], C[j], 0, 0, 0);
        C[j] = __builtin_amdgcn_mfma_f32_16x16x32_f16(a2, b[j][2], C[j], 0, 0, 0);
      }
      h16* Pp = PT + ((size_t)plane * IMGS + img) * HW;
#pragma unroll
      for (int j = 0; j < 4; ++j)
#pragma unroll
        for (int r = 0; r < 4; ++r)
          Pp[(size_t)(m0 + quad * 4 + r) * 192 + hc * 64 + j * 16 + lm] = (h16)C[j][r];
    }
  }
}

// ---------------- pass H + gated combine: no LDS, no barriers, register-batched ----------------
// grid (8 = sw x 4 qt, 128 imgs), 512 thr (8 waves: sh = wv&1, w4 = wv>>1), fully independent
// waves. Per (cand, mi): batched load a[3] + b[3][3] (12 v8h, distinct regs, in flight
// together) from L1/L2 (per-block P working set 18 KB/plane -> L1-resident), 9 MFMA (3
// chains of 3), gate-weighted accumulate. ~120 VGPR under the (512,2)=128 cap.
__global__ __launch_bounds__(512, 2) void k_gh(
    const h16* __restrict__ Kall, const h16* __restrict__ PT, const h16* __restrict__ gate,
    const float* __restrict__ hfp, h16* __restrict__ sf)
{
  const int bx = blockIdx.x;
  const int sw = bx & 1, qt = bx >> 1;
  const int img = blockIdx.y;
  const int bimg = img >> 5;
  const int tid = threadIdx.x;
  const int lane = tid & 63, wv = tid >> 6;
  const int lm = lane & 15, quad = lane >> 4;
  const int sh = wv & 1, w4 = wv >> 1;
  const int w0q = qt * 48;

  v4f acc[3][3];
#pragma unroll
  for (int mi = 0; mi < 3; ++mi)
#pragma unroll
    for (int nt = 0; nt < 3; ++nt) acc[mi][nt] = (v4f){0.f, 0.f, 0.f, 0.f};

  for (int cand = 0; cand < 6; ++cand) {
    const h16* PB = PT + ((size_t)(cand * 2 + sw) * IMGS + img) * HW;
    const h16* KB = Kall + (size_t)(cand * 2 + sh) * HW;
    const h16* g16 = gate + (size_t)(bimg * 6 + cand) * HW;
#pragma unroll
    for (int mi = 0; mi < 3; ++mi) {
      const int m0 = w4 * 48 + mi * 16;          // h' tile base
      int ktr = (m0 - 24) >> 5; ktr = ktr < 0 ? 0 : (ktr > 3 ? 3 : ktr);
      const int kb = ktr * 32 + quad * 8;        // runtime base folds into ADDRESSES only
      const h16* kr = KB + (size_t)(m0 + lm) * 192 + kb;
      v8h a0 = *(const v8h*)(kr);
      v8h a1 = *(const v8h*)(kr + 32);
      v8h a2 = *(const v8h*)(kr + 64);
      v8h b[3][3];
#pragma unroll
      for (int nt = 0; nt < 3; ++nt) {
        const h16* pr = PB + (size_t)(w0q + nt * 16 + lm) * 192 + kb;
        b[nt][0] = *(const v8h*)(pr);
        b[nt][1] = *(const v8h*)(pr + 32);
        b[nt][2] = *(const v8h*)(pr + 64);
      }
      const int hr0 = m0 + quad * 4;
      float g[3][4];
#pragma unroll
      for (int nt = 0; nt < 3; ++nt)
#pragma unroll
        for (int r = 0; r < 4; ++r)
          g[nt][r] = (float)g16[(size_t)(hr0 + r) * 192 + w0q + nt * 16 + lm];
      v4f C[3];
#pragma unroll
      for (int nt = 0; nt < 3; ++nt) C[nt] = (v4f){0.f, 0.f, 0.f, 0.f};
#pragma unroll
      for (int nt = 0; nt < 3; ++nt) {
        C[nt] = __builtin_amdgcn_mfma_f32_16x16x32_f16(a0, b[nt][0], C[nt], 0, 0, 0);
        C[nt] = __builtin_amdgcn_mfma_f32_16x16x32_f16(a1, b[nt][1], C[nt], 0, 0, 0);
        C[nt] = __builtin_amdgcn_mfma_f32_16x16x32_f16(a2, b[nt][2], C[nt], 0, 0, 0);
      }
#pragma unroll
      for (int nt = 0; nt < 3; ++nt)
#pragma unroll
        for (int r = 0; r < 4; ++r)
          acc[mi][nt][r] += g[nt][r] * C[nt][r];
    }
  }
  // epilogue: hf fold + fp16 store (each wave owns its (sh, w4))
  const float hfv = hfp[0];
  const int s = sw * 2 + sh;
  const float f = (s == 0) ? 1.f : hfv;
  h16* Op = sf + ((size_t)img * 4 + s) * HW;
#pragma unroll
  for (int mi = 0; mi < 3; ++mi) {
    const int hr0 = w4 * 48 + mi * 16 + quad * 4;
#pragma unroll
    for (int nt = 0; nt < 3; ++nt) {
      const int wc = w0q + nt * 16 + lm;
#pragma unroll
      for (int r = 0; r < 4; ++r)
        Op[(size_t)(hr0 + r) * 192 + wc] = (h16)(f * acc[mi][nt][r]);
    }
  }
}

// ---------------- final 1x1 projection 128 -> 32 (2 px/thread, v2h loads) ----------------
__global__ __launch_bounds__(256) void k_proj(
    const h16* __restrict__ sf, const float* __restrict__ pw,
    const float* __restrict__ pb, float* __restrict__ out)
{
  const int tid = threadIdx.x;
  const int lane = tid & 63;
  const int og = __builtin_amdgcn_readfirstlane(tid >> 6);   // 0..3, wave-uniform scalar
  const int b = blockIdx.x / 288;                             // 288 blocks per image (128 px each)
  const int p = (blockIdx.x - b * 288) * 128 + lane * 2;
  const h16* sfb = sf + (size_t)(b * 128) * HW + p;
  const float* pwb = pw + og * 8 * 128;                       // scalar base
  float acc0[8], acc1[8];
#pragma unroll
  for (int oo = 0; oo < 8; ++oo) { acc0[oo] = 0.f; acc1[oo] = 0.f; }
#pragma unroll 4
  for (int ch = 0; ch < 128; ++ch) {
    v2h hv = *(const v2h*)(sfb + (size_t)ch * HW);
    const float v0 = (float)hv[0], v1 = (float)hv[1];
#pragma unroll
    for (int oo = 0; oo < 8; ++oo) {
      const float w = pwb[oo * 128 + ch];
      acc0[oo] = fmaf(w, v0, acc0[oo]);
      acc1[oo] = fmaf(w, v1, acc1[oo]);
    }
  }
#pragma unroll
  for (int oo = 0; oo < 8; ++oo) {
    float2 o2;
    o2.x = acc0[oo] + pb[og * 8 + oo];
    o2.y = acc1[oo] + pb[og * 8 + oo];
    *(float2*)(out + (size_t)(b * 32 + og * 8 + oo) * HW + p) = o2;
  }
}

extern "C" void kernel_launch(void* const* d_in, const int* in_sizes, int n_in,
                              void* d_out, int out_size, void* d_ws, size_t ws_size,
                              hipStream_t stream) {
  (void)in_sizes; (void)n_in; (void)out_size; (void)ws_size;
  const float* x    = (const float*)d_in[0];
  const float* gw1  = (const float*)d_in[1];
  const float* gb1  = (const float*)d_in[2];
  const float* gw2  = (const float*)d_in[3];
  const float* gb2  = (const float*)d_in[4];
  const float* s53A = (const float*)d_in[5];
  const float* s53D = (const float*)d_in[6];
  const float* s97A = (const float*)d_in[7];
  const float* s97D = (const float*)d_in[8];
  const float* hfp  = (const float*)d_in[9];
  const float* pw   = (const float*)d_in[10];
  const float* pb   = (const float*)d_in[11];
  float* out = (float*)d_out;

  // workspace (bytes), total 153,649,152 (proven size):
  //   gate fp16:          0 ..   1,769,472   (4 x 6 x HW)
  //   Kall fp16:  1,769,472 ..   2,654,208   (12 x 192 x 192)
  //   PT   fp16:  2,654,208 .. 115,900,416   (12 x 128 x HW)  layout [plane][img][w'192][h192]
  //   sf   fp16: 115,900,416 .. 153,649,152  (128 x 4 x HW)
  h16* gate = (h16*)d_ws;
  h16* Kall = (h16*)((char*)d_ws + 1769472);
  h16* PT   = (h16*)((char*)d_ws + 2654208);
  h16* sf   = (h16*)((char*)d_ws + 115900416);

  hipLaunchKernelGGL(k_gate, dim3(576), dim3(256), 0, stream, x, gw1, gb1, gw2, gb2, gate);
  hipLaunchKernelGGL(k_build, dim3(192, 12), dim3(64), 0, stream, Kall, s53A, s53D, s97A, s97D);
  hipLaunchKernelGGL(k_gw, dim3(12, IMGS), dim3(64), 0, stream, x, Kall, PT);
  hipLaunchKernelGGL(k_gh, dim3(8, IMGS), dim3(512), 0, stream, Kall, PT, gate, hfp, sf);
  hipLaunchKernelGGL(k_proj, dim3(1152), dim3(256), 0, stream, sf, pw, pb, out);
}